// Round 7
// baseline (266.671 us; speedup 1.0000x reference)
//
#include <hip/hip_runtime.h>
#include <math.h>

#define B_  32
#define S_  4096
#define E_  256
#define A_  256
#define DE_ 512

typedef __attribute__((ext_vector_type(8)))  short short8;
typedef __attribute__((ext_vector_type(16))) float f32x16;

__device__ inline unsigned short f2bf(float x) {
    unsigned int u = __float_as_uint(x);
    u += 0x7FFFu + ((u >> 16) & 1u);      // round-to-nearest-even
    return (unsigned short)(u >> 16);
}
__device__ inline float tanh_fast(float x) {
    x = fminf(fmaxf(x, -15.f), 15.f);
    float t = __expf(2.f * x);
    return (t - 1.f) * __builtin_amdgcn_rcpf(t + 1.f);
}

// ---- Prep: block 0..63 = pack We hi/lo bf16 for the K=16-chunk layout:
// unit = c*1024 + plane*512 + kh*256 + a  (c=0..15 chunk, kh = k-half of 8),
// 8 bf16 per unit = We[a][c*16 + kh*8 .. +8].
// block 64..95 = proj; block 96 = zero attended region.
__global__ __launch_bounds__(256) void prep_kernel(
    const float* __restrict__ W, const float* __restrict__ dh,
    const float* __restrict__ bias, unsigned short* __restrict__ wepk,
    float* __restrict__ proj, float* __restrict__ out)
{
    __shared__ float dh_lds[E_];
    const int bk  = blockIdx.x;
    const int tid = threadIdx.x;
    if (bk < 64) {
        const int idx   = bk * 256 + tid;   // unit 0..16383
        const int c     = idx >> 10;
        const int r     = idx & 1023;
        const int plane = r >> 9;           // 0 = hi, 1 = lo
        const int kh    = (r >> 8) & 1;
        const int a     = r & 255;
        const float* src = W + (size_t)a * DE_ + E_ + c * 16 + kh * 8;
        unsigned int pk[4];
        #pragma unroll
        for (int j = 0; j < 4; ++j) {
            float x0 = src[2 * j], x1 = src[2 * j + 1];
            unsigned int u0 = __float_as_uint(x0) & 0xFFFF0000u;
            unsigned int u1 = __float_as_uint(x1) & 0xFFFF0000u;
            if (plane) {
                unsigned short l0 = f2bf(x0 - __uint_as_float(u0));
                unsigned short l1 = f2bf(x1 - __uint_as_float(u1));
                pk[j] = (unsigned int)l0 | ((unsigned int)l1 << 16);
            } else {
                pk[j] = (u0 >> 16) | u1;
            }
        }
        *(uint4*)&wepk[(size_t)idx * 8] = make_uint4(pk[0], pk[1], pk[2], pk[3]);
    } else if (bk < 96) {
        const int b = bk - 64;
        const int a = tid;
        dh_lds[a] = dh[b * E_ + a];
        __syncthreads();
        float acc = bias[a];
        const float* wrow = W + (size_t)a * DE_;
        #pragma unroll
        for (int d = 0; d < E_; d += 4) {
            float4 w = *(const float4*)(wrow + d);
            acc += dh_lds[d] * w.x + dh_lds[d+1] * w.y
                 + dh_lds[d+2] * w.z + dh_lds[d+3] * w.w;
        }
        proj[b * A_ + a] = acc;
    } else {
        #pragma unroll
        for (int j = tid; j < B_ * E_; j += 256) out[j] = 0.f;
    }
}

// ---- Scores: 32x32x16 MFMA, K=16 chunks, full double-buffer, 1 barrier/chunk.
// Block = 64 s x 256 a (4 waves, wave = 64s x 64a = 2x2 tiles of 32x32).
// Pipeline per iter c: barrier (staged c now visible; DMA/loads from iter c-1
// landed) -> issue DMA we(c+1), ds_write eo(c+1) (regs), global-load eo(c+2)
// -> frag reads + 12 MFMA on chunk c. Every memory op has one full iteration
// in flight before the vmcnt(0) at the next barrier.
__global__ __launch_bounds__(256, 3) void scores_kernel(
    const float* __restrict__ eo, const unsigned short* __restrict__ wepk,
    const float* __restrict__ proj,
    float* __restrict__ scores, float* __restrict__ nsq)
{
    // pool: webuf 2x1024 units @0 (32768 B); eobuf 2x256 units @32768 (8192 B)
    // webuf unit = buf*1024 + plane*512 + kh*256 + a
    // eobuf unit = buf*256  + plane*128 + kh*64  + row
    // epilogue overlay: red[64][129] @0 (33024 B); npart @33024; qpart @34048
    __shared__ __align__(16) unsigned char pool[40960];
    unsigned short* webuf = (unsigned short*)pool;
    unsigned short* eobuf = (unsigned short*)(pool + 32768);

    const int tid = threadIdx.x;
    const int b   = blockIdx.x & (B_ - 1);
    const int s0  = (blockIdx.x >> 5) * 64;
    const int w   = tid >> 6, l = tid & 63;
    const int h   = l >> 5;          // k-half for frags
    const int n32 = l & 31;

    // eo staging map: 4 lanes per row; q = kh*2 + half (16 B float4 each)
    const int erow = tid >> 2;
    const int eq   = tid & 3;
    const int ekh  = eq >> 1, ehalf = eq & 1;
    const float* ebase = eo + (size_t)(s0 + erow) * (B_ * E_) + b * E_ + eq * 4;

    const float pr0 = proj[b * A_ + w * 64 + n32];
    const float pr1 = proj[b * A_ + w * 64 + 32 + n32];

    f32x16 acc[2][2];
    #pragma unroll
    for (int i = 0; i < 2; ++i)
        #pragma unroll
        for (int j = 0; j < 2; ++j)
            #pragma unroll
            for (int r = 0; r < 16; ++r) acc[i][j][r] = 0.f;
    float nacc = 0.f;

    // stage one chunk's 4 floats: split + 2x ds_write_b64 (hi, lo planes)
    auto stage_eo = [&](int buf, float4 v) {
        nacc += v.x*v.x + v.y*v.y + v.z*v.z + v.w*v.w;
        unsigned int ux = __float_as_uint(v.x) & 0xFFFF0000u;
        unsigned int uy = __float_as_uint(v.y) & 0xFFFF0000u;
        unsigned int uz = __float_as_uint(v.z) & 0xFFFF0000u;
        unsigned int uw = __float_as_uint(v.w) & 0xFFFF0000u;
        unsigned int hp0 = (ux >> 16) | uy;
        unsigned int hp1 = (uz >> 16) | uw;
        unsigned int lp0 = (unsigned int)f2bf(v.x - __uint_as_float(ux))
                         | ((unsigned int)f2bf(v.y - __uint_as_float(uy)) << 16);
        unsigned int lp1 = (unsigned int)f2bf(v.z - __uint_as_float(uz))
                         | ((unsigned int)f2bf(v.w - __uint_as_float(uw)) << 16);
        const int u = buf * 256 + ekh * 64 + erow;
        *(uint2*)&eobuf[(size_t)u * 8 + ehalf * 4]         = make_uint2(hp0, hp1);
        *(uint2*)&eobuf[(size_t)(u + 128) * 8 + ehalf * 4] = make_uint2(lp0, lp1);
    };
    auto dma_we = [&](int c, int buf) {
        const unsigned short* gsrc = wepk + (size_t)c * 1024 * 8;
        #pragma unroll
        for (int it = 0; it < 4; ++it) {
            const int u = it * 256 + tid;
            __builtin_amdgcn_global_load_lds(
                (const __attribute__((address_space(1))) void*)(gsrc + (size_t)u * 8),
                (__attribute__((address_space(3))) void*)&webuf[(size_t)(buf * 1024 + u) * 8],
                16, 0, 0);
        }
    };

    // prologue: chunk 0 staged, chunk 1 in regs
    float4 eA = *(const float4*)(ebase);          // even chunks
    dma_we(0, 0);
    stage_eo(0, eA);                              // waits eA via compiler vmcnt
    float4 eB = *(const float4*)(ebase + 16);     // odd chunks

    #pragma unroll 2
    for (int c = 0; c < 16; ++c) {
        const int rb = c & 1;
        __syncthreads();   // staged chunk c visible; iter c-1's DMA/loads landed
        if (c < 15) {
            dma_we(c + 1, rb ^ 1);
            stage_eo(rb ^ 1, rb ? eA : eB);       // chunk c+1 parity: odd->eB, even->eA
        }
        if (c < 14) {
            float4 nv = *(const float4*)(ebase + (c + 2) * 16);
            if (rb) eB = nv; else eA = nv;        // chunk c+2 parity == c parity
        }
        // frags + 12 MFMA on chunk c
        short8 ah[2], al[2], bh[2], bl[2];
        #pragma unroll
        for (int nt = 0; nt < 2; ++nt) {
            const int bu = rb * 1024 + h * 256 + w * 64 + nt * 32 + n32;
            bh[nt] = *(const short8*)&webuf[(size_t)bu * 8];
            bl[nt] = *(const short8*)&webuf[(size_t)(bu + 512) * 8];
        }
        #pragma unroll
        for (int mt = 0; mt < 2; ++mt) {
            const int au = rb * 256 + h * 64 + mt * 32 + n32;
            ah[mt] = *(const short8*)&eobuf[(size_t)au * 8];
            al[mt] = *(const short8*)&eobuf[(size_t)(au + 128) * 8];
        }
        #pragma unroll
        for (int mt = 0; mt < 2; ++mt)
            #pragma unroll
            for (int nt = 0; nt < 2; ++nt) {
                acc[mt][nt] = __builtin_amdgcn_mfma_f32_32x32x16_bf16(ah[mt], bh[nt], acc[mt][nt], 0, 0, 0);
                acc[mt][nt] = __builtin_amdgcn_mfma_f32_32x32x16_bf16(ah[mt], bl[nt], acc[mt][nt], 0, 0, 0);
                acc[mt][nt] = __builtin_amdgcn_mfma_f32_32x32x16_bf16(al[mt], bh[nt], acc[mt][nt], 0, 0, 0);
            }
    }
    __syncthreads();   // all frag reads done before LDS overlay

    // ---- epilogue: tanh + reduce over a
    float* red   = (float*)pool;            // [64 rows][129]
    float* npart = (float*)(pool + 33024);  // 256 floats
    float* qpart = (float*)(pool + 34048);  // 256 floats
    #pragma unroll
    for (int mt = 0; mt < 2; ++mt) {
        #pragma unroll
        for (int r = 0; r < 16; ++r) {
            // C/D layout (m74/m101): col = lane&31, row = (r&3)+8*(r>>2)+4*h
            const int rowl = (r & 3) + 8 * (r >> 2) + 4 * h;
            float v = tanh_fast(pr0 + acc[mt][0][r])
                    + tanh_fast(pr1 + acc[mt][1][r]);
            red[(mt * 32 + rowl) * 129 + w * 32 + n32] = v;
        }
    }
    npart[tid] = nacc;
    __syncthreads();
    {   // 256 threads: (row = tid>>2, q = tid&3) sums 32 of 128 cols, q-rotated
        const int row = tid >> 2, q = tid & 3;
        float s = 0.f;
        #pragma unroll
        for (int j = 0; j < 32; ++j)
            s += red[row * 129 + q * 32 + ((j + q * 8) & 31)];
        qpart[tid] = s;
    }
    __syncthreads();
    if (tid < 64) {
        scores[b * S_ + s0 + tid] = qpart[4*tid] + qpart[4*tid+1]
                                  + qpart[4*tid+2] + qpart[4*tid+3];
        nsq[b * S_ + s0 + tid]    = npart[4*tid] + npart[4*tid+1]
                                  + npart[4*tid+2] + npart[4*tid+3];
    }
}

// ---- Attend (softmax fused): per-b softmax stats recomputed per block from
// L2-hot scores, then 128-row partial of attended + attn_map rows.
__global__ __launch_bounds__(256) void attend_kernel(
    const float* __restrict__ eo, const float* __restrict__ scores,
    const float* __restrict__ nsq, float* __restrict__ out)
{
    __shared__ float red[256];
    __shared__ float4 acc_red[4][64];
    const int tid = threadIdx.x;
    const int b   = blockIdx.x & (B_ - 1);
    const int ch  = blockIdx.x / B_;

    float v[16];
    float m = -1e30f;
    #pragma unroll
    for (int i = 0; i < 16; ++i) {
        v[i] = scores[b * S_ + i * 256 + tid];
        m = fmaxf(m, v[i]);
    }
    red[tid] = m;
    __syncthreads();
    for (int off = 128; off > 0; off >>= 1) {
        if (tid < off) red[tid] = fmaxf(red[tid], red[tid + off]);
        __syncthreads();
    }
    m = red[0];
    __syncthreads();
    float sum = 0.f;
    #pragma unroll
    for (int i = 0; i < 16; ++i) sum += __expf(v[i] - m);
    red[tid] = sum;
    __syncthreads();
    for (int off = 128; off > 0; off >>= 1) {
        if (tid < off) red[tid] += red[tid + off];
        __syncthreads();
    }
    const float inv = 1.f / red[0];

    const int le = tid & 63, sg = tid >> 6;
    const int s0 = ch * 128 + sg * 32;
    float4 a = make_float4(0.f, 0.f, 0.f, 0.f);
    #pragma unroll 8
    for (int s = 0; s < 32; ++s) {
        float pv = __expf(scores[b * S_ + s0 + s] - m) * inv;
        float4 e = *(const float4*)(eo + (size_t)(s0 + s) * (B_ * E_)
                                       + b * E_ + le * 4);
        a.x = fmaf(pv, e.x, a.x);
        a.y = fmaf(pv, e.y, a.y);
        a.z = fmaf(pv, e.z, a.z);
        a.w = fmaf(pv, e.w, a.w);
    }
    acc_red[sg][le] = a;
    if (tid < 128) {
        const int s = ch * 128 + tid;
        float pv = __expf(scores[b * S_ + s] - m) * inv;
        out[B_ * E_ + b * S_ + s] = pv * sqrtf(nsq[b * S_ + s]);
    }
    __syncthreads();
    if (tid < 64) {
        float4 a0 = acc_red[0][tid], a1 = acc_red[1][tid];
        float4 a2 = acc_red[2][tid], a3 = acc_red[3][tid];
        float* dst = out + b * E_ + tid * 4;
        atomicAdd(dst + 0, a0.x + a1.x + a2.x + a3.x);
        atomicAdd(dst + 1, a0.y + a1.y + a2.y + a3.y);
        atomicAdd(dst + 2, a0.z + a1.z + a2.z + a3.z);
        atomicAdd(dst + 3, a0.w + a1.w + a2.w + a3.w);
    }
}

extern "C" void kernel_launch(void* const* d_in, const int* in_sizes, int n_in,
                              void* d_out, int out_size, void* d_ws, size_t ws_size,
                              hipStream_t stream)
{
    const float* dh   = (const float*)d_in[0];  // (1,B,D)
    const float* eo   = (const float*)d_in[1];  // (S,B,E)
    const float* W    = (const float*)d_in[2];  // (A, D+E)
    const float* bias = (const float*)d_in[3];  // (A,)
    float* out = (float*)d_out;                 // [attended 8192 | attn_map 131072]
    float* ws  = (float*)d_ws;

    float* projb  = ws;                           // 8192 floats
    float* nsqb   = ws + 8192;                    // 131072 floats
    float* scores = nsqb + S_ * B_;               // 131072 floats
    unsigned short* wepk = (unsigned short*)(scores + S_ * B_);  // 256 KB packed We

    prep_kernel   <<<97,              256, 0, stream>>>(W, dh, bias, wepk, projb, out);
    scores_kernel <<<B_ * (S_ / 64),  256, 0, stream>>>(eo, wepk, projb, scores, nsqb);
    attend_kernel <<<B_ * (S_ / 128), 256, 0, stream>>>(eo, scores, nsqb, out);
}